// Round 1
// baseline (217.111 us; speedup 1.0000x reference)
//
#include <hip/hip_runtime.h>
#include <cstdint>
#include <cstddef>

// ConcreteLayer forward: out = x @ softmax_rows((W + gumbel(U))/T)
// Reformulated: d_i = sum_k exp(l_ik);  out = (x * (1/d)^T_broadcast) @ exp(l)
//   (max-subtraction dropped: l <= ~18, exp fits fp32; folds exactly into d)
// B=4096, IN=4096, OUT=1024. bf16 MFMA GEMM.
// ws: xb (bf16 x', 32MB) | bt (bf16 exp(l)^T [OUT,IN], 8MB) | d (4096 f32 row sums)

#define TINYF 1.17549435082228750797e-38f
#define LN2F 0.69314718055994530942f
#define LOG2EF 1.44269504088896340736f

typedef unsigned short u16;
typedef __attribute__((ext_vector_type(8))) short bf16x8;
typedef __attribute__((ext_vector_type(4))) float f32x4;

__device__ __forceinline__ u16 f2bf(float f) {
  union { float f; uint32_t u; } v; v.f = f;
  uint32_t r = v.u + 0x7FFFu + ((v.u >> 16) & 1u);  // RNE
  return (u16)(r >> 16);
}

__device__ __forceinline__ float log2_hw(float x) { return __builtin_amdgcn_logf(x); }
__device__ __forceinline__ float exp2_hw(float x) { return __builtin_amdgcn_exp2f(x); }

// g = -ln(-ln(u)) = -ln2 * log2(ln2 * (-log2 u))
__device__ __forceinline__ float gumbel_fast(float u) {
  float t = -log2_hw(u);
  return -LN2F * log2_hw(t * LN2F);
}
__device__ __forceinline__ float exp_fast(float x) { return exp2_hw(x * LOG2EF); }

__device__ __forceinline__ void gld_lds16(const void* g, void* l) {
  __builtin_amdgcn_global_load_lds(
      (__attribute__((address_space(1))) void*)(g),
      (__attribute__((address_space(3))) void*)(l), 16, 0, 0);
}

// ---------------- kernel 1: exp-transpose + row-sum accumulate ----------------
// Per 64x64 tile of l: e = exp((W+G)/T); write e^T as bf16 to BT; atomicAdd row sums to d.
__global__ void trans_exp_kernel(const float* __restrict__ W, const float* __restrict__ U,
                                 const float* __restrict__ Tp, u16* __restrict__ BT,
                                 float* __restrict__ d) {
  __shared__ float tile[64][65];
  const int k0 = blockIdx.x * 64, n0 = blockIdx.y * 64;
  const int t = threadIdx.x;
  const float invT = 1.0f / Tp[0];
  {
    const int nn4 = (t & 15) * 4, kq = t >> 4;   // 16 rows per pass, float4 cols
#pragma unroll
    for (int r = 0; r < 4; ++r) {
      int kk = r * 16 + kq;
      size_t gi = (size_t)(k0 + kk) * 1024 + (n0 + nn4);
      float4 w = *(const float4*)&W[gi];
      float4 u = *(const float4*)&U[gi];
      float e0 = exp_fast((w.x + gumbel_fast(u.x * (1.0f - TINYF) + TINYF)) * invT);
      float e1 = exp_fast((w.y + gumbel_fast(u.y * (1.0f - TINYF) + TINYF)) * invT);
      float e2 = exp_fast((w.z + gumbel_fast(u.z * (1.0f - TINYF) + TINYF)) * invT);
      float e3 = exp_fast((w.w + gumbel_fast(u.w * (1.0f - TINYF) + TINYF)) * invT);
      tile[kk][nn4 + 0] = e0; tile[kk][nn4 + 1] = e1;
      tile[kk][nn4 + 2] = e2; tile[kk][nn4 + 3] = e3;
      // partial row sum over this thread's 4 cols; reduce across the 16 lanes sharing kk
      float s = (e0 + e1) + (e2 + e3);
#pragma unroll
      for (int m = 8; m > 0; m >>= 1) s += __shfl_xor(s, m, 16);
      if ((t & 15) == 0) atomicAdd(&d[k0 + kk], s);
    }
  }
  __syncthreads();
  {
    const int kk4 = (t & 15) * 4, nq = t >> 4;
#pragma unroll
    for (int r = 0; r < 4; ++r) {
      int nn = r * 16 + nq;
      ushort4 o;
      o.x = f2bf(tile[kk4 + 0][nn]);
      o.y = f2bf(tile[kk4 + 1][nn]);
      o.z = f2bf(tile[kk4 + 2][nn]);
      o.w = f2bf(tile[kk4 + 3][nn]);
      *(ushort4*)&BT[(size_t)(n0 + nn) * 4096 + (k0 + kk4)] = o;
    }
  }
}

// ---------------- kernel 2: x' = x / d (bf16), fused with zeroing d_out ----------------
__global__ void cast_zero_kernel(const float4* __restrict__ x, const float4* __restrict__ d4,
                                 ushort4* __restrict__ xb, float4* __restrict__ out,
                                 int n4x, int n4o) {
  int i = blockIdx.x * blockDim.x + threadIdx.x;
  if (i < n4x) {
    int col4 = i & 1023;                 // 1024 float4 per x-row; col index into d
    float4 v = x[i];
    float4 dd = d4[col4];
    ushort4 o;
    o.x = f2bf(v.x / dd.x); o.y = f2bf(v.y / dd.y);
    o.z = f2bf(v.z / dd.z); o.w = f2bf(v.w / dd.w);
    xb[i] = o;
  } else {
    int j = i - n4x;
    if (j < n4o) out[j] = make_float4(0.f, 0.f, 0.f, 0.f);
  }
}

// ---------------- kernel 3: GEMM 128x128 tile, TK=64, XOR-swizzled LDS, split-K=4 ----------------
// LDS granule g of row r holds global 16B-granule (g ^ (r&7)) -> fragment ds_read_b128
// hits 8 distinct bank groups (2-way aliasing = free), staging stays lane-contiguous.
// Split-K=4: 32x8x4 = 1024 blocks -> ~4 co-resident blocks/CU (LDS 32KB -> cap 5,
// VGPR 92 -> cap 5). The 2-barrier structure needs >=3 blocks/CU of wave-overlap
// to hide the vmcnt(0)+barrier drain (m114); at 2 blocks/CU MfmaUtil was 19%.
#define TM 128
#define TN 128
#define TK 64
#define SPLITK 4

__launch_bounds__(256)
__global__ void gemm_bt_kernel(const u16* __restrict__ A, const u16* __restrict__ BT,
                               float* __restrict__ C, int M, int N, int K) {
  __shared__ u16 As[TM * TK];  // 16 KB
  __shared__ u16 Bs[TN * TK];  // 16 KB

  const int tid = threadIdx.x;
  const int lane = tid & 63, w = tid >> 6;
  const int wm = w >> 1, wn = w & 1;           // 2x2 wave grid, 64x64 per wave
  const int m0 = blockIdx.x * TM, n0 = blockIdx.y * TN;
  const int quad = lane >> 4, r16 = lane & 15;
  const int srow = lane >> 3;                  // staging: row within 8-row chunk
  const int sg = (lane & 7) ^ srow;            // staging: swizzled 16B granule in row

  const int kz = blockIdx.z;                   // split-K = 4
  const int Kh = K / SPLITK;
  const u16* Ak = A + (size_t)kz * Kh;
  const u16* Bk = BT + (size_t)kz * Kh;

  f32x4 acc[4][4] = {};

  for (int kt = 0; kt < Kh; kt += TK) {
    __syncthreads();
#pragma unroll
    for (int c = 0; c < 4; ++c) {
      int chunk = w * 4 + c;                   // 0..15, 8 rows x 64k each (1 KB)
      gld_lds16(Ak + (size_t)(m0 + chunk * 8 + srow) * K + kt + sg * 8, (char*)As + chunk * 1024);
      gld_lds16(Bk + (size_t)(n0 + chunk * 8 + srow) * K + kt + sg * 8, (char*)Bs + chunk * 1024);
    }
    __syncthreads();

#pragma unroll
    for (int ss = 0; ss < 2; ++ss) {           // two K=32 sub-steps per staged TK=64
      bf16x8 aF[4], bF[4];
#pragma unroll
      for (int mi = 0; mi < 4; ++mi) {
        int row = wm * 64 + mi * 16 + r16;
        aF[mi] = *(const bf16x8*)((const char*)As + row * 128 + (((ss * 4 + quad) ^ (row & 7)) * 16));
      }
#pragma unroll
      for (int ni = 0; ni < 4; ++ni) {
        int row = wn * 64 + ni * 16 + r16;
        bF[ni] = *(const bf16x8*)((const char*)Bs + row * 128 + (((ss * 4 + quad) ^ (row & 7)) * 16));
      }
#pragma unroll
      for (int mi = 0; mi < 4; ++mi)
#pragma unroll
        for (int ni = 0; ni < 4; ++ni)
          acc[mi][ni] = __builtin_amdgcn_mfma_f32_16x16x32_bf16(aF[mi], bF[ni], acc[mi][ni], 0, 0, 0);
    }
  }

  // epilogue: C/D layout col = lane&15, row = quad*4 + reg
#pragma unroll
  for (int mi = 0; mi < 4; ++mi)
#pragma unroll
    for (int ni = 0; ni < 4; ++ni)
#pragma unroll
      for (int r = 0; r < 4; ++r) {
        int row = m0 + wm * 64 + mi * 16 + quad * 4 + r;
        int col = n0 + wn * 64 + ni * 16 + r16;
        atomicAdd(&C[(size_t)row * N + col], acc[mi][ni][r]);
      }
}

extern "C" void kernel_launch(void* const* d_in, const int* in_sizes, int n_in,
                              void* d_out, int out_size, void* d_ws, size_t ws_size,
                              hipStream_t stream) {
  const int M = 4096, K = 4096, N = 1024;  // B, IN, OUT
  const float* x = (const float*)d_in[0];
  const float* W = (const float*)d_in[1];
  const float* U = (const float*)d_in[2];
  const float* Tp = (const float*)d_in[3];
  float* out = (float*)d_out;

  char* ws = (char*)d_ws;
  u16* xb = (u16*)ws;                                          // 32 MB
  u16* bt = (u16*)(ws + (size_t)M * K * 2);                    // 8 MB
  float* dsum = (float*)(ws + (size_t)M * K * 2 + (size_t)N * K * 2);  // 16 KB

  hipMemsetAsync(dsum, 0, K * sizeof(float), stream);
  trans_exp_kernel<<<dim3(K / 64, N / 64), 256, 0, stream>>>(W, U, Tp, bt, dsum);
  const int n4x = M * K / 4, n4o = M * N / 4;
  cast_zero_kernel<<<dim3((n4x + n4o) / 256), 256, 0, stream>>>(
      (const float4*)x, (const float4*)dsum, (ushort4*)xb, (float4*)out, n4x, n4o);
  gemm_bt_kernel<<<dim3(M / TM, N / TN, SPLITK), 256, 0, stream>>>(xb, bt, out, M, N, K);
}

// Round 2
// 196.405 us; speedup vs baseline: 1.1054x; 1.1054x over previous
//
#include <hip/hip_runtime.h>
#include <cstdint>
#include <cstddef>

// ConcreteLayer forward: out = x @ softmax_rows((W + gumbel(U))/T)
// Reformulated: d_i = sum_k exp(l_ik);  out = (x * (1/d)^T_broadcast) @ exp(l)
//   (max-subtraction dropped: l <= ~18, exp fits fp32; folds exactly into d)
// B=4096, IN=4096, OUT=1024. bf16 MFMA GEMM.
// ws: xb (bf16 x', 32MB) | bt (bf16 exp(l)^T [OUT,IN], 8MB) | d (4096 f32 row sums)

#define TINYF 1.17549435082228750797e-38f
#define LN2F 0.69314718055994530942f
#define LOG2EF 1.44269504088896340736f

typedef unsigned short u16;
typedef __attribute__((ext_vector_type(8))) short bf16x8;
typedef __attribute__((ext_vector_type(4))) float f32x4;

__device__ __forceinline__ u16 f2bf(float f) {
  union { float f; uint32_t u; } v; v.f = f;
  uint32_t r = v.u + 0x7FFFu + ((v.u >> 16) & 1u);  // RNE
  return (u16)(r >> 16);
}

__device__ __forceinline__ float log2_hw(float x) { return __builtin_amdgcn_logf(x); }
__device__ __forceinline__ float exp2_hw(float x) { return __builtin_amdgcn_exp2f(x); }

// g = -ln(-ln(u)) = -ln2 * log2(ln2 * (-log2 u))
__device__ __forceinline__ float gumbel_fast(float u) {
  float t = -log2_hw(u);
  return -LN2F * log2_hw(t * LN2F);
}
__device__ __forceinline__ float exp_fast(float x) { return exp2_hw(x * LOG2EF); }

__device__ __forceinline__ void gld_lds16(const void* g, void* l) {
  __builtin_amdgcn_global_load_lds(
      (__attribute__((address_space(1))) void*)(g),
      (__attribute__((address_space(3))) void*)(l), 16, 0, 0);
}

// ---------------- kernel 1: exp-transpose + row-sum accumulate ----------------
// Per 64x64 tile of l: e = exp((W+G)/T); write e^T as bf16 to BT; atomicAdd row sums to d.
__global__ void trans_exp_kernel(const float* __restrict__ W, const float* __restrict__ U,
                                 const float* __restrict__ Tp, u16* __restrict__ BT,
                                 float* __restrict__ d) {
  __shared__ float tile[64][65];
  const int k0 = blockIdx.x * 64, n0 = blockIdx.y * 64;
  const int t = threadIdx.x;
  const float invT = 1.0f / Tp[0];
  {
    const int nn4 = (t & 15) * 4, kq = t >> 4;   // 16 rows per pass, float4 cols
#pragma unroll
    for (int r = 0; r < 4; ++r) {
      int kk = r * 16 + kq;
      size_t gi = (size_t)(k0 + kk) * 1024 + (n0 + nn4);
      float4 w = *(const float4*)&W[gi];
      float4 u = *(const float4*)&U[gi];
      float e0 = exp_fast((w.x + gumbel_fast(u.x * (1.0f - TINYF) + TINYF)) * invT);
      float e1 = exp_fast((w.y + gumbel_fast(u.y * (1.0f - TINYF) + TINYF)) * invT);
      float e2 = exp_fast((w.z + gumbel_fast(u.z * (1.0f - TINYF) + TINYF)) * invT);
      float e3 = exp_fast((w.w + gumbel_fast(u.w * (1.0f - TINYF) + TINYF)) * invT);
      tile[kk][nn4 + 0] = e0; tile[kk][nn4 + 1] = e1;
      tile[kk][nn4 + 2] = e2; tile[kk][nn4 + 3] = e3;
      // partial row sum over this thread's 4 cols; reduce across the 16 lanes sharing kk
      float s = (e0 + e1) + (e2 + e3);
#pragma unroll
      for (int m = 8; m > 0; m >>= 1) s += __shfl_xor(s, m, 16);
      if ((t & 15) == 0) atomicAdd(&d[k0 + kk], s);
    }
  }
  __syncthreads();
  {
    const int kk4 = (t & 15) * 4, nq = t >> 4;
#pragma unroll
    for (int r = 0; r < 4; ++r) {
      int nn = r * 16 + nq;
      ushort4 o;
      o.x = f2bf(tile[kk4 + 0][nn]);
      o.y = f2bf(tile[kk4 + 1][nn]);
      o.z = f2bf(tile[kk4 + 2][nn]);
      o.w = f2bf(tile[kk4 + 3][nn]);
      *(ushort4*)&BT[(size_t)(n0 + nn) * 4096 + (k0 + kk4)] = o;
    }
  }
}

// ---------------- kernel 2: x' = x / d (bf16), fused with zeroing d_out ----------------
__global__ void cast_zero_kernel(const float4* __restrict__ x, const float4* __restrict__ d4,
                                 ushort4* __restrict__ xb, float4* __restrict__ out,
                                 int n4x, int n4o) {
  int i = blockIdx.x * blockDim.x + threadIdx.x;
  if (i < n4x) {
    int col4 = i & 1023;                 // 1024 float4 per x-row; col index into d
    float4 v = x[i];
    float4 dd = d4[col4];
    ushort4 o;
    o.x = f2bf(v.x / dd.x); o.y = f2bf(v.y / dd.y);
    o.z = f2bf(v.z / dd.z); o.w = f2bf(v.w / dd.w);
    xb[i] = o;
  } else {
    int j = i - n4x;
    if (j < n4o) out[j] = make_float4(0.f, 0.f, 0.f, 0.f);
  }
}

// ---------------- kernel 3: GEMM 128x128 tile, TK=64, XOR-swizzled LDS, split-K=2 ----------------
// 2-phase double-buffered pipeline (T3-minimum): stage(next tile) is issued BEFORE
// compute(current), so HBM latency of the global_load_lds hides under ds_read+MFMA;
// ONE __syncthreads (vmcnt(0)+lgkmcnt(0) drain + barrier) per K-tile instead of two.
// LDS granule g of row r holds global 16B-granule (g ^ (r&7)) -> fragment ds_read_b128
// hits 8 distinct bank groups (2-way aliasing = free), staging stays lane-contiguous.
// LDS 64KB (2 bufs) -> 2 blocks/CU; VGPR ~92 -> not the cap.
#define TM 128
#define TN 128
#define TK 64
#define SPLITK 2

__launch_bounds__(256)
__global__ void gemm_bt_kernel(const u16* __restrict__ A, const u16* __restrict__ BT,
                               float* __restrict__ C, int M, int N, int K) {
  __shared__ u16 As[2][TM * TK];  // 2 x 16 KB
  __shared__ u16 Bs[2][TN * TK];  // 2 x 16 KB

  const int tid = threadIdx.x;
  const int lane = tid & 63, w = tid >> 6;
  const int wm = w >> 1, wn = w & 1;           // 2x2 wave grid, 64x64 per wave
  const int m0 = blockIdx.x * TM, n0 = blockIdx.y * TN;
  const int quad = lane >> 4, r16 = lane & 15;
  const int srow = lane >> 3;                  // staging: row within 8-row chunk
  const int sg = (lane & 7) ^ srow;            // staging: swizzled 16B granule in row

  const int kz = blockIdx.z;                   // split-K = 2
  const int Kh = K / SPLITK;
  const u16* Ak = A + (size_t)kz * Kh;
  const u16* Bk = BT + (size_t)kz * Kh;

  f32x4 acc[4][4] = {};

#define STAGE(buf, kt)                                                                   \
  {                                                                                      \
    _Pragma("unroll") for (int c = 0; c < 4; ++c) {                                      \
      int chunk = w * 4 + c; /* 0..15, 8 rows x 64k each (1 KB) */                       \
      gld_lds16(Ak + (size_t)(m0 + chunk * 8 + srow) * K + (kt) + sg * 8,                \
                (char*)&As[buf][0] + chunk * 1024);                                      \
      gld_lds16(Bk + (size_t)(n0 + chunk * 8 + srow) * K + (kt) + sg * 8,                \
                (char*)&Bs[buf][0] + chunk * 1024);                                      \
    }                                                                                    \
  }

#define COMPUTE(buf)                                                                     \
  {                                                                                      \
    _Pragma("unroll") for (int ss = 0; ss < 2; ++ss) {                                   \
      bf16x8 aF[4], bF[4];                                                               \
      _Pragma("unroll") for (int mi = 0; mi < 4; ++mi) {                                 \
        int row = wm * 64 + mi * 16 + r16;                                               \
        aF[mi] = *(const bf16x8*)((const char*)&As[buf][0] + row * 128 +                 \
                                  (((ss * 4 + quad) ^ (row & 7)) * 16));                 \
      }                                                                                  \
      _Pragma("unroll") for (int ni = 0; ni < 4; ++ni) {                                 \
        int row = wn * 64 + ni * 16 + r16;                                               \
        bF[ni] = *(const bf16x8*)((const char*)&Bs[buf][0] + row * 128 +                 \
                                  (((ss * 4 + quad) ^ (row & 7)) * 16));                 \
      }                                                                                  \
      _Pragma("unroll") for (int mi = 0; mi < 4; ++mi)                                   \
          _Pragma("unroll") for (int ni = 0; ni < 4; ++ni)                               \
              acc[mi][ni] =                                                              \
          __builtin_amdgcn_mfma_f32_16x16x32_bf16(aF[mi], bF[ni], acc[mi][ni], 0, 0, 0); \
    }                                                                                    \
  }

  // nt = Kh/TK = 32 tiles (even). Prologue stages tile 0; steady loop processes 2
  // tiles/iter with compile-time buffer indices; epilogue computes last two tiles.
  STAGE(0, 0)
  __syncthreads();
  const int nt = Kh / TK;
  for (int t = 0; t < nt - 2; t += 2) {
    STAGE(1, (t + 1) * TK)
    COMPUTE(0)
    __syncthreads();
    STAGE(0, (t + 2) * TK)
    COMPUTE(1)
    __syncthreads();
  }
  STAGE(1, (nt - 1) * TK)
  COMPUTE(0)
  __syncthreads();
  COMPUTE(1)

#undef STAGE
#undef COMPUTE

  // epilogue: C/D layout col = lane&15, row = quad*4 + reg
#pragma unroll
  for (int mi = 0; mi < 4; ++mi)
#pragma unroll
    for (int ni = 0; ni < 4; ++ni)
#pragma unroll
      for (int r = 0; r < 4; ++r) {
        int row = m0 + wm * 64 + mi * 16 + quad * 4 + r;
        int col = n0 + wn * 64 + ni * 16 + r16;
        atomicAdd(&C[(size_t)row * N + col], acc[mi][ni][r]);
      }
}

extern "C" void kernel_launch(void* const* d_in, const int* in_sizes, int n_in,
                              void* d_out, int out_size, void* d_ws, size_t ws_size,
                              hipStream_t stream) {
  const int M = 4096, K = 4096, N = 1024;  // B, IN, OUT
  const float* x = (const float*)d_in[0];
  const float* W = (const float*)d_in[1];
  const float* U = (const float*)d_in[2];
  const float* Tp = (const float*)d_in[3];
  float* out = (float*)d_out;

  char* ws = (char*)d_ws;
  u16* xb = (u16*)ws;                                          // 32 MB
  u16* bt = (u16*)(ws + (size_t)M * K * 2);                    // 8 MB
  float* dsum = (float*)(ws + (size_t)M * K * 2 + (size_t)N * K * 2);  // 16 KB

  hipMemsetAsync(dsum, 0, K * sizeof(float), stream);
  trans_exp_kernel<<<dim3(K / 64, N / 64), 256, 0, stream>>>(W, U, Tp, bt, dsum);
  const int n4x = M * K / 4, n4o = M * N / 4;
  cast_zero_kernel<<<dim3((n4x + n4o) / 256), 256, 0, stream>>>(
      (const float4*)x, (const float4*)dsum, (ushort4*)xb, (float4*)out, n4x, n4o);
  gemm_bt_kernel<<<dim3(M / TM, N / TN, SPLITK), 256, 0, stream>>>(xb, bt, out, M, N, K);
}

// Round 3
// 192.716 us; speedup vs baseline: 1.1266x; 1.0191x over previous
//
#include <hip/hip_runtime.h>
#include <cstdint>
#include <cstddef>

// ConcreteLayer forward: out = x @ softmax_rows((W + gumbel(U))/T)
// Reformulation v2 (dependency-broken):
//   e[i,k]   = exp((W+G)/T)          (stored bf16, UNSCALED, transposed -> BT [OUT,IN])
//   dpart[t,i] = partial row sums of e over OUT-tile t   (non-atomic, exclusive writes)
//   bt_scale:  BT[k,i] *= 1/sum_t dpart[t,i]             (16 MB pass)
//   out = bf16(x) @ BT                                   (MFMA GEMM, split-K=2 atomics)
// This removes the memset, the d atomics, and the serial dependency of the 96 MB
// x-cast on trans_exp: prep is ONE fused kernel (trans | x-cast | out-zero).
// B=4096, IN=4096, OUT=1024.
// ws: xb (bf16 x, 32MB) | bt (bf16 e^T [OUT,IN], 8MB) | dpart ([16][4096] f32, 256KB)

#define TINYF 1.17549435082228750797e-38f
#define LN2F 0.69314718055994530942f
#define LOG2EF 1.44269504088896340736f

typedef unsigned short u16;
typedef __attribute__((ext_vector_type(8))) short bf16x8;
typedef __attribute__((ext_vector_type(4))) float f32x4;

__device__ __forceinline__ u16 f2bf(float f) {
  union { float f; uint32_t u; } v; v.f = f;
  uint32_t r = v.u + 0x7FFFu + ((v.u >> 16) & 1u);  // RNE
  return (u16)(r >> 16);
}
__device__ __forceinline__ float bf2f(u16 h) {
  union { float f; uint32_t u; } v; v.u = ((uint32_t)h) << 16;
  return v.f;
}

__device__ __forceinline__ float log2_hw(float x) { return __builtin_amdgcn_logf(x); }
__device__ __forceinline__ float exp2_hw(float x) { return __builtin_amdgcn_exp2f(x); }

// g = -ln(-ln(u)) = -ln2 * log2(ln2 * (-log2 u))
__device__ __forceinline__ float gumbel_fast(float u) {
  float t = -log2_hw(u);
  return -LN2F * log2_hw(t * LN2F);
}
__device__ __forceinline__ float exp_fast(float x) { return exp2_hw(x * LOG2EF); }

__device__ __forceinline__ void gld_lds16(const void* g, void* l) {
  __builtin_amdgcn_global_load_lds(
      (__attribute__((address_space(1))) void*)(g),
      (__attribute__((address_space(3))) void*)(l), 16, 0, 0);
}

// ---------------- kernel 1: fused prep ----------------
// blocks [0, 1024): 64x64 exp-transpose tiles of l -> BT (unscaled) + dpart sums
// blocks [1024, 1024+16384): x f32 -> bf16 cast (no scaling)
// blocks [1024+16384, +4096): zero out (split-K accumulator)
#define NB_TRANS 1024
#define NB_CAST 16384
#define NB_ZERO 4096

__global__ void prep_kernel(const float* __restrict__ W, const float* __restrict__ U,
                            const float* __restrict__ Tp, const float4* __restrict__ x,
                            u16* __restrict__ BT, float* __restrict__ dpart,
                            ushort4* __restrict__ xb, float4* __restrict__ out) {
  __shared__ float tile[64][65];
  const int bx = blockIdx.x;
  const int t = threadIdx.x;

  if (bx < NB_TRANS) {
    // ---- exp-transpose tile: k0 = IN-row tile (64 of them), n0 = OUT-col tile (16)
    const int k0 = (bx & 63) * 64, n0 = (bx >> 6) * 64;
    const float invT = 1.0f / Tp[0];
    {
      const int nn4 = (t & 15) * 4, kq = t >> 4;  // 16 rows per pass, float4 cols
#pragma unroll
      for (int r = 0; r < 4; ++r) {
        int kk = r * 16 + kq;
        size_t gi = (size_t)(k0 + kk) * 1024 + (n0 + nn4);
        float4 w = *(const float4*)&W[gi];
        float4 u = *(const float4*)&U[gi];
        float e0 = exp_fast((w.x + gumbel_fast(u.x * (1.0f - TINYF) + TINYF)) * invT);
        float e1 = exp_fast((w.y + gumbel_fast(u.y * (1.0f - TINYF) + TINYF)) * invT);
        float e2 = exp_fast((w.z + gumbel_fast(u.z * (1.0f - TINYF) + TINYF)) * invT);
        float e3 = exp_fast((w.w + gumbel_fast(u.w * (1.0f - TINYF) + TINYF)) * invT);
        tile[kk][nn4 + 0] = e0; tile[kk][nn4 + 1] = e1;
        tile[kk][nn4 + 2] = e2; tile[kk][nn4 + 3] = e3;
        // partial row sum over this thread's 4 cols; reduce across 16 lanes sharing kk
        float s = (e0 + e1) + (e2 + e3);
#pragma unroll
        for (int m = 8; m > 0; m >>= 1) s += __shfl_xor(s, m, 16);
        // exclusive (n-tile, row) slot: no atomics, no pre-zeroing needed
        if ((t & 15) == 0) dpart[(bx >> 6) * 4096 + k0 + kk] = s;
      }
    }
    __syncthreads();
    {
      const int kk4 = (t & 15) * 4, nq = t >> 4;
#pragma unroll
      for (int r = 0; r < 4; ++r) {
        int nn = r * 16 + nq;
        ushort4 o;
        o.x = f2bf(tile[kk4 + 0][nn]);
        o.y = f2bf(tile[kk4 + 1][nn]);
        o.z = f2bf(tile[kk4 + 2][nn]);
        o.w = f2bf(tile[kk4 + 3][nn]);
        *(ushort4*)&BT[(size_t)(n0 + nn) * 4096 + (k0 + kk4)] = o;
      }
    }
  } else if (bx < NB_TRANS + NB_CAST) {
    // ---- x f32 -> bf16 (unscaled; 1/d now lives on the BT side)
    int i = (bx - NB_TRANS) * 256 + t;
    float4 v = x[i];
    ushort4 o;
    o.x = f2bf(v.x); o.y = f2bf(v.y); o.z = f2bf(v.z); o.w = f2bf(v.w);
    xb[i] = o;
  } else {
    // ---- zero split-K accumulator
    int j = (bx - NB_TRANS - NB_CAST) * 256 + t;
    out[j] = make_float4(0.f, 0.f, 0.f, 0.f);
  }
}

// ---------------- kernel 2: BT[k,i] *= 1/d_i ----------------
// Block: 128 IN-cols x 128 OUT-rows. Redundantly reduces dpart for its 128 cols
// (16x128 f32 = 8KB, L2-resident), then streams 32KB of BT through the scale.
__global__ void bt_scale_kernel(u16* __restrict__ BT, const float* __restrict__ dpart) {
  __shared__ float invd[128];
  const int c0 = blockIdx.x * 128;  // IN col tile (32)
  const int r0 = blockIdx.y * 128;  // OUT row tile (8)
  const int t = threadIdx.x;
  if (t < 128) {
    float s = 0.f;
#pragma unroll
    for (int p = 0; p < 16; ++p) s += dpart[p * 4096 + c0 + t];
    invd[t] = 1.0f / s;
  }
  __syncthreads();
  const int cv = (t & 15) * 8, rq = t >> 4;
  const float4 ia = *(const float4*)&invd[cv];
  const float4 ib = *(const float4*)&invd[cv + 4];
#pragma unroll
  for (int pass = 0; pass < 8; ++pass) {
    int row = r0 + pass * 16 + rq;
    size_t gi = (size_t)row * 4096 + c0 + cv;
    ushort4 a = *(ushort4*)&BT[gi];
    ushort4 b = *(ushort4*)&BT[gi + 4];
    ushort4 oa, ob;
    oa.x = f2bf(bf2f(a.x) * ia.x); oa.y = f2bf(bf2f(a.y) * ia.y);
    oa.z = f2bf(bf2f(a.z) * ia.z); oa.w = f2bf(bf2f(a.w) * ia.w);
    ob.x = f2bf(bf2f(b.x) * ib.x); ob.y = f2bf(bf2f(b.y) * ib.y);
    ob.z = f2bf(bf2f(b.z) * ib.z); ob.w = f2bf(bf2f(b.w) * ib.w);
    *(ushort4*)&BT[gi] = oa;
    *(ushort4*)&BT[gi + 4] = ob;
  }
}

// ---------------- kernel 3: GEMM 128x128 tile, TK=64, XOR-swizzled LDS, split-K=2 ----------------
// Known-good R0 structure (505 TF at this shape): single-buffered, two barriers/K-tile.
// R1 (split-K=4) and R2 (2-phase dbuf) were both neutral-to-negative; see journal.
// LDS granule g of row r holds global 16B-granule (g ^ (r&7)) -> fragment ds_read_b128
// hits 8 distinct bank groups (2-way aliasing = free), staging stays lane-contiguous.
#define TM 128
#define TN 128
#define TK 64
#define SPLITK 2

__launch_bounds__(256)
__global__ void gemm_bt_kernel(const u16* __restrict__ A, const u16* __restrict__ BT,
                               float* __restrict__ C, int M, int N, int K) {
  __shared__ u16 As[TM * TK];  // 16 KB
  __shared__ u16 Bs[TN * TK];  // 16 KB

  const int tid = threadIdx.x;
  const int lane = tid & 63, w = tid >> 6;
  const int wm = w >> 1, wn = w & 1;           // 2x2 wave grid, 64x64 per wave
  const int m0 = blockIdx.x * TM, n0 = blockIdx.y * TN;
  const int quad = lane >> 4, r16 = lane & 15;
  const int srow = lane >> 3;                  // staging: row within 8-row chunk
  const int sg = (lane & 7) ^ srow;            // staging: swizzled 16B granule in row

  const int kz = blockIdx.z;                   // split-K = 2
  const int Kh = K >> 1;
  const u16* Ak = A + (size_t)kz * Kh;
  const u16* Bk = BT + (size_t)kz * Kh;

  f32x4 acc[4][4] = {};

  for (int kt = 0; kt < Kh; kt += TK) {
    __syncthreads();
#pragma unroll
    for (int c = 0; c < 4; ++c) {
      int chunk = w * 4 + c;                   // 0..15, 8 rows x 64k each (1 KB)
      gld_lds16(Ak + (size_t)(m0 + chunk * 8 + srow) * K + kt + sg * 8, (char*)As + chunk * 1024);
      gld_lds16(Bk + (size_t)(n0 + chunk * 8 + srow) * K + kt + sg * 8, (char*)Bs + chunk * 1024);
    }
    __syncthreads();

#pragma unroll
    for (int ss = 0; ss < 2; ++ss) {           // two K=32 sub-steps per staged TK=64
      bf16x8 aF[4], bF[4];
#pragma unroll
      for (int mi = 0; mi < 4; ++mi) {
        int row = wm * 64 + mi * 16 + r16;
        aF[mi] = *(const bf16x8*)((const char*)As + row * 128 + (((ss * 4 + quad) ^ (row & 7)) * 16));
      }
#pragma unroll
      for (int ni = 0; ni < 4; ++ni) {
        int row = wn * 64 + ni * 16 + r16;
        bF[ni] = *(const bf16x8*)((const char*)Bs + row * 128 + (((ss * 4 + quad) ^ (row & 7)) * 16));
      }
#pragma unroll
      for (int mi = 0; mi < 4; ++mi)
#pragma unroll
        for (int ni = 0; ni < 4; ++ni)
          acc[mi][ni] = __builtin_amdgcn_mfma_f32_16x16x32_bf16(aF[mi], bF[ni], acc[mi][ni], 0, 0, 0);
    }
  }

  // epilogue: C/D layout col = lane&15, row = quad*4 + reg
#pragma unroll
  for (int mi = 0; mi < 4; ++mi)
#pragma unroll
    for (int ni = 0; ni < 4; ++ni)
#pragma unroll
      for (int r = 0; r < 4; ++r) {
        int row = m0 + wm * 64 + mi * 16 + quad * 4 + r;
        int col = n0 + wn * 64 + ni * 16 + r16;
        atomicAdd(&C[(size_t)row * N + col], acc[mi][ni][r]);
      }
}

extern "C" void kernel_launch(void* const* d_in, const int* in_sizes, int n_in,
                              void* d_out, int out_size, void* d_ws, size_t ws_size,
                              hipStream_t stream) {
  const int M = 4096, K = 4096, N = 1024;  // B, IN, OUT
  const float* x = (const float*)d_in[0];
  const float* W = (const float*)d_in[1];
  const float* U = (const float*)d_in[2];
  const float* Tp = (const float*)d_in[3];
  float* out = (float*)d_out;

  char* ws = (char*)d_ws;
  u16* xb = (u16*)ws;                                          // 32 MB
  u16* bt = (u16*)(ws + (size_t)M * K * 2);                    // 8 MB
  float* dpart = (float*)(ws + (size_t)M * K * 2 + (size_t)N * K * 2);  // 256 KB

  prep_kernel<<<dim3(NB_TRANS + NB_CAST + NB_ZERO), 256, 0, stream>>>(
      W, U, Tp, (const float4*)x, bt, dpart, (ushort4*)xb, (float4*)out);
  bt_scale_kernel<<<dim3(32, 8), 256, 0, stream>>>(bt, dpart);
  gemm_bt_kernel<<<dim3(M / TM, N / TN, SPLITK), 256, 0, stream>>>(xb, bt, out, M, N, K);
}